// Round 2
// baseline (317.713 us; speedup 1.0000x reference)
//
#include <hip/hip_runtime.h>

// ---------------------------------------------------------------------------
// MultiHeadAttention  B=2,S=4096,D=512,H=8,dk=64 — bf16 MFMA pipeline.
//   1) gemm_proj<f32,0>: Q = (q@Wq^T+bq)*CSC -> ws [B,H,S,64] bf16 (pre-scaled!)
//   2) gemm_proj<f32,0>: K                   -> ws [B,H,S,64] bf16
//   3) gemm_proj<f32,1>: V                   -> ws [B,H,64,S] bf16 (transposed)
//   4) attn_kernel: LDS-free flash attention (direct-global K/V, in-register
//      P transpose via cvt_pk+permlane, defer-rescale)  -> Ctx bf16
//   5) gemm_proj<bf16,2>: out = Ctx@Wo^T+bo -> fp32
// ---------------------------------------------------------------------------

#define DM   512
#define NH   8
#define DK   64
#define SEQ  4096
#define BATCH 2
#define MROWS (BATCH*SEQ)
#define CSC  0.18033688011112042f   // log2(e)/sqrt(64)

typedef __attribute__((ext_vector_type(4))) float  f32x4;
typedef __attribute__((ext_vector_type(8))) short  s16x8;
typedef __attribute__((ext_vector_type(4))) short  s16x4;
typedef __attribute__((ext_vector_type(4))) unsigned short u16x4;
typedef __attribute__((ext_vector_type(4))) int    i32x4;

static __device__ __forceinline__ unsigned short f2bf(float f) {
    union { float f; unsigned int u; } a; a.f = f;
    unsigned int r = a.u + 0x7FFFu + ((a.u >> 16) & 1u);   // RNE
    return (unsigned short)(r >> 16);
}
static __device__ __forceinline__ int cvtpk(float lo, float hi) {
    int r;
    asm("v_cvt_pk_bf16_f32 %0, %1, %2" : "=v"(r) : "v"(lo), "v"(hi));
    return r;
}
static __device__ __forceinline__ float fexp2(float x) {
    float r;
    asm("v_exp_f32 %0, %1" : "=v"(r) : "v"(x));
    return r;
}
static __device__ __forceinline__ void swap32(int &a, int &b) {
    auto t = __builtin_amdgcn_permlane32_swap(a, b, false, false);
    a = t[0]; b = t[1];
}
static __device__ __forceinline__ void swap16(int &a, int &b) {
    auto t = __builtin_amdgcn_permlane16_swap(a, b, false, false);
    a = t[0]; b = t[1];
}

// ---------------------------------------------------------------------------
// GEMM: C[m,n] = (sum_k A[m,k]*W[n,k] + bias[n]) * oscale
// 128x128 tile, BK=32, 4 waves (2x2), each wave 64x64 via 4x4 16x16x32 MFMA.
// ---------------------------------------------------------------------------
template<bool A_BF16, int OUT_MODE>
__global__ __launch_bounds__(256)
void gemm_proj(const void* __restrict__ Aptr,
               const float* __restrict__ W,
               const float* __restrict__ bias,
               void* __restrict__ outp, float oscale)
{
    __shared__ short As[128 * 40];
    __shared__ short Bs[128 * 40];

    const int tid  = threadIdx.x;
    const int lane = tid & 63;
    const int wid  = tid >> 6;
    const int g = lane >> 4, r = lane & 15;
    const int wm = wid >> 1, wn = wid & 1;
    const int brow = blockIdx.x * 128;
    const int bcol = blockIdx.y * 128;

    f32x4 acc[4][4];
    #pragma unroll
    for (int i = 0; i < 4; ++i)
        #pragma unroll
        for (int j = 0; j < 4; ++j) acc[i][j] = (f32x4)(0.0f);

    for (int k0 = 0; k0 < DM; k0 += 32) {
        if (A_BF16) {
            const short* A = (const short*)Aptr;
            #pragma unroll
            for (int j = 0; j < 2; ++j) {
                int c = tid + 256 * j;
                int row = c >> 2, cc = c & 3;
                s16x8 v = *(const s16x8*)(A + (size_t)(brow + row) * DM + k0 + cc * 8);
                *(s16x8*)(&As[row * 40 + cc * 8]) = v;
            }
        } else {
            const float* A = (const float*)Aptr;
            #pragma unroll
            for (int j = 0; j < 4; ++j) {
                int c = tid + 256 * j;
                int row = c >> 3, cc = c & 7;
                f32x4 v = *(const f32x4*)(A + (size_t)(brow + row) * DM + k0 + cc * 4);
                s16x4 b;
                b[0] = (short)f2bf(v[0]); b[1] = (short)f2bf(v[1]);
                b[2] = (short)f2bf(v[2]); b[3] = (short)f2bf(v[3]);
                *(s16x4*)(&As[row * 40 + cc * 4]) = b;
            }
        }
        #pragma unroll
        for (int j = 0; j < 4; ++j) {
            int c = tid + 256 * j;
            int row = c >> 3, cc = c & 7;
            f32x4 v = *(const f32x4*)(W + (size_t)(bcol + row) * DM + k0 + cc * 4);
            s16x4 b;
            b[0] = (short)f2bf(v[0]); b[1] = (short)f2bf(v[1]);
            b[2] = (short)f2bf(v[2]); b[3] = (short)f2bf(v[3]);
            *(s16x4*)(&Bs[row * 40 + cc * 4]) = b;
        }
        __syncthreads();

        s16x8 af[4], bfr[4];
        #pragma unroll
        for (int mf = 0; mf < 4; ++mf)
            af[mf] = *(const s16x8*)(&As[(wm * 64 + mf * 16 + r) * 40 + g * 8]);
        #pragma unroll
        for (int nf = 0; nf < 4; ++nf)
            bfr[nf] = *(const s16x8*)(&Bs[(wn * 64 + nf * 16 + r) * 40 + g * 8]);
        #pragma unroll
        for (int mf = 0; mf < 4; ++mf)
            #pragma unroll
            for (int nf = 0; nf < 4; ++nf)
                acc[mf][nf] = __builtin_amdgcn_mfma_f32_16x16x32_bf16(
                    af[mf], bfr[nf], acc[mf][nf], 0, 0, 0);
        __syncthreads();
    }

    const int ncolbase = bcol + wn * 64;
    const int mrowbase = brow + wm * 64;
    #pragma unroll
    for (int mf = 0; mf < 4; ++mf) {
        #pragma unroll
        for (int nf = 0; nf < 4; ++nf) {
            const int ncol = ncolbase + nf * 16 + r;
            const int m0   = mrowbase + mf * 16 + g * 4;
            const float bv = bias[ncol];
            if (OUT_MODE == 2) {
                float* O = (float*)outp;
                #pragma unroll
                for (int i = 0; i < 4; ++i)
                    O[(size_t)(m0 + i) * DM + ncol] = (acc[mf][nf][i] + bv) * oscale;
            } else if (OUT_MODE == 0) {
                unsigned short* O = (unsigned short*)outp;
                const int h = ncol >> 6, d = ncol & 63;
                #pragma unroll
                for (int i = 0; i < 4; ++i) {
                    int m = m0 + i;
                    int b = m >> 12, s = m & (SEQ - 1);
                    O[((size_t)(b * NH + h) * SEQ + s) * DK + d] =
                        f2bf((acc[mf][nf][i] + bv) * oscale);
                }
            } else {
                unsigned short* O = (unsigned short*)outp;
                const int h = ncol >> 6, d = ncol & 63;
                const int b = m0 >> 12, s0 = m0 & (SEQ - 1);
                u16x4 pk;
                #pragma unroll
                for (int i = 0; i < 4; ++i) pk[i] = f2bf((acc[mf][nf][i] + bv) * oscale);
                *(u16x4*)(&O[((size_t)(b * NH + h) * DK + d) * SEQ + s0]) = pk;
            }
        }
    }
}

// ---------------------------------------------------------------------------
// LDS-free flash attention, swapped orientation.
//   S^T  = mfma(A=K[t,d],  B=Q[q,d])  -> C[t,q], col(lane&15)=q
//   ctx^T= mfma(A=Vt[d,t], B=P[q,t])  -> C[d,q], col(lane&15)=q
// Wave owns 32 q-rows (qf=2). K double-buffered in regs (prefetch t+64 after
// QK^T); V issued at body start. P reaches B-fragment layout in-register:
// per (qf,h): 4x v_cvt_pk_bf16_f32 + 2x permlane32_swap + 2x permlane16_swap.
// Q is pre-scaled by CSC -> p = exp2(s - m), raw v_exp_f32.
// ---------------------------------------------------------------------------
__global__ __launch_bounds__(256, 2)
void attn_kernel(const unsigned short* __restrict__ Qw,
                 const unsigned short* __restrict__ Kw,
                 const unsigned short* __restrict__ Vtw,
                 unsigned short* __restrict__ Ctx)
{
    const int tid  = threadIdx.x;
    const int lane = tid & 63;
    const int wid  = tid >> 6;
    const int g = lane >> 4, r = lane & 15;
    const int q0 = blockIdx.x * 128 + wid * 32;
    const int bh = blockIdx.y;
    const short* Qp = (const short*)Qw  + (size_t)bh * SEQ * DK;
    const short* Kp = (const short*)Kw  + (size_t)bh * SEQ * DK;
    const short* Vp = (const short*)Vtw + (size_t)bh * DK * SEQ;

    s16x8 qfr[2][2];
    #pragma unroll
    for (int qf = 0; qf < 2; ++qf)
        #pragma unroll
        for (int df = 0; df < 2; ++df)
            qfr[qf][df] = *(const s16x8*)(Qp + (size_t)(q0 + qf * 16 + r) * DK + df * 32 + g * 8);

    f32x4 o[4][2];
    #pragma unroll
    for (int df = 0; df < 4; ++df)
        #pragma unroll
        for (int qf = 0; qf < 2; ++qf) o[df][qf] = (f32x4)(0.0f);
    float mrun[2] = {-1e30f, -1e30f};
    float lrun[2] = {0.0f, 0.0f};

    const int laneK = r * DK + g * 8;
    const int laneV = r * SEQ + g * 8;

    s16x8 kf[2][4][2];   // double-buffered K fragments
    s16x8 vf[4][2];

    #pragma unroll
    for (int tf = 0; tf < 4; ++tf)
        #pragma unroll
        for (int h = 0; h < 2; ++h)
            kf[0][tf][h] = *(const s16x8*)(Kp + tf * 16 * DK + laneK + h * 32);

#define ATT_BODY(T0, CB, NB)                                                     \
  {                                                                              \
    _Pragma("unroll")                                                            \
    for (int df = 0; df < 4; ++df)                                               \
      _Pragma("unroll")                                                          \
      for (int h = 0; h < 2; ++h)                                                \
        vf[df][h] = *(const s16x8*)(Vp + df * 16 * SEQ + laneV + (T0) + h * 32); \
    f32x4 s[4][2];                                                               \
    _Pragma("unroll")                                                            \
    for (int tf = 0; tf < 4; ++tf)                                               \
      _Pragma("unroll")                                                          \
      for (int qf = 0; qf < 2; ++qf) s[tf][qf] = (f32x4)(0.0f);                  \
    _Pragma("unroll")                                                            \
    for (int tf = 0; tf < 4; ++tf)                                               \
      _Pragma("unroll")                                                          \
      for (int qf = 0; qf < 2; ++qf) {                                           \
        s[tf][qf] = __builtin_amdgcn_mfma_f32_16x16x32_bf16(kf[CB][tf][0], qfr[qf][0], s[tf][qf], 0, 0, 0); \
        s[tf][qf] = __builtin_amdgcn_mfma_f32_16x16x32_bf16(kf[CB][tf][1], qfr[qf][1], s[tf][qf], 0, 0, 0); \
      }                                                                          \
    if ((T0) + 64 < SEQ) {                                                       \
      _Pragma("unroll")                                                          \
      for (int tf = 0; tf < 4; ++tf)                                             \
        _Pragma("unroll")                                                        \
        for (int h = 0; h < 2; ++h)                                              \
          kf[NB][tf][h] = *(const s16x8*)(Kp + ((T0) + 64 + tf * 16) * DK + laneK + h * 32); \
    }                                                                            \
    _Pragma("unroll")                                                            \
    for (int qf = 0; qf < 2; ++qf) {                                             \
      float mx = s[0][qf][0];                                                    \
      _Pragma("unroll")                                                          \
      for (int tf = 0; tf < 4; ++tf)                                             \
        _Pragma("unroll")                                                        \
        for (int i = 0; i < 4; ++i) mx = fmaxf(mx, s[tf][qf][i]);                \
      mx = fmaxf(mx, __shfl_xor(mx, 16));                                        \
      mx = fmaxf(mx, __shfl_xor(mx, 32));                                        \
      if (!__all(mx <= mrun[qf] + 1.5f)) {                                       \
        float mnew = fmaxf(mrun[qf], mx);                                        \
        float al = fexp2(mrun[qf] - mnew);                                       \
        mrun[qf] = mnew; lrun[qf] *= al;                                         \
        _Pragma("unroll")                                                        \
        for (int df = 0; df < 4; ++df) o[df][qf] *= al;                          \
      }                                                                          \
      const float mm = mrun[qf]; float rs = 0.0f;                                \
      _Pragma("unroll")                                                          \
      for (int tf = 0; tf < 4; ++tf)                                             \
        _Pragma("unroll")                                                        \
        for (int i = 0; i < 4; ++i) {                                            \
          float p = fexp2(s[tf][qf][i] - mm); s[tf][qf][i] = p; rs += p;         \
        }                                                                        \
      rs += __shfl_xor(rs, 16); rs += __shfl_xor(rs, 32);                        \
      lrun[qf] += rs;                                                            \
    }                                                                            \
    s16x8 pb[2][2];                                                              \
    _Pragma("unroll")                                                            \
    for (int qf = 0; qf < 2; ++qf)                                               \
      _Pragma("unroll")                                                          \
      for (int h = 0; h < 2; ++h) {                                              \
        int A0 = cvtpk(s[2 * h][qf][0],     s[2 * h][qf][1]);                    \
        int A1 = cvtpk(s[2 * h][qf][2],     s[2 * h][qf][3]);                    \
        int A2 = cvtpk(s[2 * h + 1][qf][0], s[2 * h + 1][qf][1]);                \
        int A3 = cvtpk(s[2 * h + 1][qf][2], s[2 * h + 1][qf][3]);                \
        swap32(A0, A2); swap16(A0, A2);                                          \
        swap32(A1, A3); swap16(A1, A3);                                          \
        i32x4 w; w[0] = A0; w[1] = A1; w[2] = A2; w[3] = A3;                     \
        pb[qf][h] = __builtin_bit_cast(s16x8, w);                                \
      }                                                                          \
    _Pragma("unroll")                                                            \
    for (int df = 0; df < 4; ++df)                                               \
      _Pragma("unroll")                                                          \
      for (int qf = 0; qf < 2; ++qf) {                                           \
        o[df][qf] = __builtin_amdgcn_mfma_f32_16x16x32_bf16(vf[df][0], pb[qf][0], o[df][qf], 0, 0, 0); \
        o[df][qf] = __builtin_amdgcn_mfma_f32_16x16x32_bf16(vf[df][1], pb[qf][1], o[df][qf], 0, 0, 0); \
      }                                                                          \
  }

    for (int t0 = 0; t0 < SEQ; t0 += 128) {
        ATT_BODY(t0, 0, 1)
        ATT_BODY(t0 + 64, 1, 0)
    }
#undef ATT_BODY

    const int b = bh >> 3, h2 = bh & 7;
    #pragma unroll
    for (int qf = 0; qf < 2; ++qf) {
        const float inv = 1.0f / lrun[qf];
        const int q = q0 + qf * 16 + r;
        const size_t rowoff = (size_t)(b * SEQ + q) * DM + h2 * DK;
        #pragma unroll
        for (int df = 0; df < 4; ++df) {
            u16x4 pk;
            #pragma unroll
            for (int i = 0; i < 4; ++i) pk[i] = f2bf(o[df][qf][i] * inv);
            *(u16x4*)(&Ctx[rowoff + df * 16 + g * 4]) = pk;
        }
    }
}

// ---------------------------------------------------------------------------
extern "C" void kernel_launch(void* const* d_in, const int* in_sizes, int n_in,
                              void* d_out, int out_size, void* d_ws, size_t ws_size,
                              hipStream_t stream)
{
    const float* q  = (const float*)d_in[0];
    const float* k  = (const float*)d_in[1];
    const float* v  = (const float*)d_in[2];
    const float* Wq = (const float*)d_in[3];
    const float* bq = (const float*)d_in[4];
    const float* Wk = (const float*)d_in[5];
    const float* bk = (const float*)d_in[6];
    const float* Wv = (const float*)d_in[7];
    const float* bv = (const float*)d_in[8];
    const float* Wo = (const float*)d_in[9];
    const float* bo = (const float*)d_in[10];

    unsigned short* ws  = (unsigned short*)d_ws;
    unsigned short* Qw  = ws;                       // [B,H,S,64] bf16, pre-scaled
    unsigned short* Kw  = Qw  + (size_t)MROWS * DM; // [B,H,S,64] bf16
    unsigned short* Vtw = Kw  + (size_t)MROWS * DM; // [B,H,64,S] bf16
    unsigned short* Ctx = Vtw + (size_t)MROWS * DM; // [B*S, 512] bf16

    dim3 gg(MROWS / 128, DM / 128);                 // (64, 4)
    gemm_proj<false, 0><<<gg, 256, 0, stream>>>(q, Wq, bq, Qw, CSC);
    gemm_proj<false, 0><<<gg, 256, 0, stream>>>(k, Wk, bk, Kw, 1.0f);
    gemm_proj<false, 1><<<gg, 256, 0, stream>>>(v, Wv, bv, Vtw, 1.0f);
    attn_kernel<<<dim3(32, 16), 256, 0, stream>>>(Qw, Kw, Vtw, Ctx);
    gemm_proj<true, 2><<<gg, 256, 0, stream>>>(Ctx, Wo, bo, d_out, 1.0f);
}